// Round 15
// baseline (701.004 us; speedup 1.0000x reference)
//
#include <hip/hip_runtime.h>

// S4 model (B=8, L=4096, H=512, N=16, 4 layers).
// Round 15:
//  - ssm keys reverted to r13 form (bl&7) — r14's sxV rework was net-negative
//    (gemm counters prove b128 reads with ro&7 key are conflict-free).
//  - ssm quartered: 128 bc per block (2 complete b's), Ul+Vl = 32 KB LDS ->
//    5 blocks/CU (20 waves/CU, was 8), grid 2048, acc[4][2].

typedef __attribute__((ext_vector_type(8))) short s16x8;
typedef __attribute__((ext_vector_type(4))) float f32x4;
typedef unsigned short u16;
typedef unsigned int u32;

#define LSEQ 4096
#define HD   512
#define NST  16
#define NLAYER 4
#define BS   8
#define LC   64
#define NCH  64
#define BC   512   // BS*NCH

static __device__ __forceinline__ u16 f2bf(float f){
  u32 u = __builtin_bit_cast(u32, f);
  u += 0x7FFFu + ((u >> 16) & 1u);
  return (u16)(u >> 16);
}
static __device__ __forceinline__ float bf2f(u16 v){
  u32 u = ((u32)v) << 16;
  return __builtin_bit_cast(float, u);
}
static __device__ __forceinline__ u32 pack2bf(float a, float b){
  return (u32)f2bf(a) | ((u32)f2bf(b) << 16);
}
static __device__ __forceinline__ float gelu_exact(float x){
  float z = fabsf(x) * 0.70710678118654752f;
  float t = 1.f / (1.f + 0.3275911f * z);
  float p = t*(0.254829592f + t*(-0.284496736f + t*(1.421413741f +
            t*(-1.453152027f + t*1.061405429f))));
  float er = 1.f - p * __expf(-z*z);
  er = (x < 0.f) ? -er : er;
  return 0.5f * x * (1.f + er);
}
static __device__ __forceinline__ void async16(const void* g, void* l){
  __builtin_amdgcn_global_load_lds((const __attribute__((address_space(1))) unsigned*)g,
                                   (__attribute__((address_space(3))) unsigned*)l,
                                   16, 0, 0);
}

// ---------------- params: w=exp(dt*A), w^LC, Ct=2*C*(w-1)/A (per layer, 65536 f) ----
__global__ __launch_bounds__(256) void param_kernel(
    const float* __restrict__ log_dt, const float* __restrict__ A_re,
    const float* __restrict__ A_im, const float* __restrict__ C_re,
    const float* __restrict__ C_im, float* __restrict__ params)
{
  int idx = blockIdx.x*256 + threadIdx.x;
  int h = idx & (HD-1);
  int n = (idx >> 9) & (NST-1);
  int layer = idx >> 13;
  float dt  = expf(log_dt[layer*HD + h]);
  float Are = A_re[((layer<<9)+h)*NST + n];
  float Aim = A_im[((layer<<9)+h)*NST + n];
  float ar = Are*dt, ai = Aim*dt;
  float er = expf(ar), sn, cs;
  sincosf(ai, &sn, &cs);
  float wr = er*cs, wi = er*sn;
  float eL = expf((float)LC*ar), snL, csL;
  sincosf((float)LC*ai, &snL, &csL);
  float* P = params + layer*65536;
  P[n*1024 + h]        = wr;
  P[n*1024 + 512 + h]  = wi;
  P[16384 + n*1024 + h]       = eL*csL;
  P[16384 + n*1024 + 512 + h] = eL*snL;
  float den = Are*Are + Aim*Aim;
  float qr = ((wr-1.f)*Are + wi*Aim) / den;
  float qi = (wi*Are - (wr-1.f)*Aim) / den;
  #pragma unroll
  for (int d=0; d<2; d++){
    float Cre = C_re[(((layer*2+d)<<9)+h)*NST + n];
    float Cim = C_im[(((layer*2+d)<<9)+h)*NST + n];
    P[32768 + (d*NST+n)*1024 + h]       = 2.f*(Cre*qr - Cim*qi);
    P[32768 + (d*NST+n)*1024 + 512 + h] = 2.f*(Cre*qi + Cim*qr);
  }
}

__global__ __launch_bounds__(256) void owconv_kernel(const float* __restrict__ ow,
                                                     u16* __restrict__ owbf)
{
  size_t idx = (size_t)blockIdx.x*256 + threadIdx.x;
  owbf[idx] = f2bf(ow[idx]);
}

// ---------------- encoder: row-wise + LN-stat partials -----------------------------
__global__ __launch_bounds__(256) void encoder_kernel(
    const float* __restrict__ x, const float* __restrict__ ew,
    const float* __restrict__ eb, float* __restrict__ hbuf,
    float2* __restrict__ pstat)
{
  int row  = (int)((blockIdx.x*256 + threadIdx.x) >> 6);   // 32768 rows
  int lane = threadIdx.x & 63;
  int t = row & (LSEQ-1);
  int b = row >> 12;
  float xv = x[(b<<12) + t];
  float g = (float)t * (1.0f/4095.0f);
  const float* ewp = ew + lane*16;
  const float* ebp = eb + lane*8;
  float hv[8], s = 0.f, sq = 0.f;
  #pragma unroll
  for (int j=0;j<8;++j){
    float v = xv*ewp[2*j] + g*ewp[2*j+1] + ebp[j];
    hv[j] = v; s += v; sq += v*v;
  }
  float4* hp = (float4*)(hbuf + ((size_t)row << 9) + lane*8);
  hp[0] = make_float4(hv[0],hv[1],hv[2],hv[3]);
  hp[1] = make_float4(hv[4],hv[5],hv[6],hv[7]);
  #pragma unroll
  for (int off=32; off; off>>=1){ s += __shfl_xor(s, off, 64); sq += __shfl_xor(sq, off, 64); }
  if (lane < 8) pstat[(size_t)row*8 + lane] = (lane==0) ? make_float2(s, sq)
                                                        : make_float2(0.f, 0.f);
}

// ---------------- lnt: stats from pstat partials + apply + transpose ---------------
__global__ __launch_bounds__(256) void lnt_kernel(
    const float* __restrict__ hbuf, const float2* __restrict__ pstat,
    const float* __restrict__ lnw, const float* __restrict__ lnb,
    u16* __restrict__ uT)
{
  __shared__ u32 tile[512*33];
  __shared__ float smu[64], srs[64];
  int bc = blockIdx.x, tid = threadIdx.x;
  const float* base = hbuf + ((size_t)bc << 15);
  if (tid < 64){
    const float2* pp = pstat + ((size_t)(bc*64 + tid))*8;
    float s = 0.f, sq = 0.f;
    #pragma unroll
    for (int j=0;j<8;++j){ float2 v = pp[j]; s += v.x; sq += v.y; }
    float mu = s*(1.f/512.f);
    float var = sq*(1.f/512.f) - mu*mu;
    smu[tid] = mu; srs[tid] = rsqrtf(var + 1e-5f);
  }
  __syncthreads();
  #pragma unroll
  for (int it=0; it<8; ++it){
    int ho = (tid & 7) + it*8;
    int tp = (tid >> 3) & 31;
    int r0 = 2*tp, r1 = 2*tp + 1;
    float mu0 = smu[r0], rs0 = srs[r0];
    float mu1 = smu[r1], rs1 = srs[r1];
    const float* pa = base + ((size_t)r0 << 9) + ho*8;
    const float* pc = base + ((size_t)r1 << 9) + ho*8;
    float4 a0 = *(const float4*)pa, a1 = *(const float4*)(pa+4);
    float4 c0 = *(const float4*)pc, c1 = *(const float4*)(pc+4);
    const float* pw = lnw + ho*8;
    const float* pb = lnb + ho*8;
    float4 w0 = *(const float4*)pw, w1 = *(const float4*)(pw+4);
    float4 b0 = *(const float4*)pb, b1 = *(const float4*)(pb+4);
    u32* td = &tile[(ho*8)*33 + tp];
    td[0*33] = pack2bf((a0.x-mu0)*rs0*w0.x+b0.x, (c0.x-mu1)*rs1*w0.x+b0.x);
    td[1*33] = pack2bf((a0.y-mu0)*rs0*w0.y+b0.y, (c0.y-mu1)*rs1*w0.y+b0.y);
    td[2*33] = pack2bf((a0.z-mu0)*rs0*w0.z+b0.z, (c0.z-mu1)*rs1*w0.z+b0.z);
    td[3*33] = pack2bf((a0.w-mu0)*rs0*w0.w+b0.w, (c0.w-mu1)*rs1*w0.w+b0.w);
    td[4*33] = pack2bf((a1.x-mu0)*rs0*w1.x+b1.x, (c1.x-mu1)*rs1*w1.x+b1.x);
    td[5*33] = pack2bf((a1.y-mu0)*rs0*w1.y+b1.y, (c1.y-mu1)*rs1*w1.y+b1.y);
    td[6*33] = pack2bf((a1.z-mu0)*rs0*w1.z+b1.z, (c1.z-mu1)*rs1*w1.z+b1.z);
    td[7*33] = pack2bf((a1.w-mu0)*rs0*w1.w+b1.w, (c1.w-mu1)*rs1*w1.w+b1.w);
  }
  __syncthreads();
  #pragma unroll
  for (int it=0; it<16; ++it){
    int linear = it*256 + tid;
    int h = linear >> 3, sg = linear & 7;
    uint4 v = *(const uint4*)&tile[h*33 + sg*4];
    *(uint4*)(uT + ((size_t)h*BC + bc)*64 + sg*8) = v;
  }
}

// ---------------- build: A_h = [M|E] (64x128) and W_h (64x64), bf16, 256 thr -------
__global__ __launch_bounds__(256) void build_kernel(
    const float* __restrict__ logdt, const float* __restrict__ Are_,
    const float* __restrict__ Aim_, const float* __restrict__ P,
    const float* __restrict__ Dv, u16* __restrict__ Abuf, u16* __restrict__ Wbuf)
{
  __shared__ float pr[65][17], pi[65][17];
  __shared__ float kp0[4][64], kp1[4][64];
  __shared__ float kk0[64], kk1[64];
  int h = blockIdx.x;
  int tid = threadIdx.x;
  int d = tid & 63, ng = tid >> 6;
  float dt = expf(logdt[h]);
  float k0p = 0.f, k1p = 0.f;
  #pragma unroll
  for (int j=0; j<4; ++j){
    int n = ng*4 + j;
    float ar = Are_[h*NST+n]*dt, ai = Aim_[h*NST+n]*dt;
    float er = expf(ar*(float)d), sn, cs;
    sincosf(ai*(float)d, &sn, &cs);
    float wr = er*cs, wi = er*sn;
    pr[d][n] = wr; pi[d][n] = wi;
    if (d == 63){
      float er2 = expf(ar*64.f), sn2, cs2;
      sincosf(ai*64.f, &sn2, &cs2);
      pr[64][n] = er2*cs2; pi[64][n] = er2*sn2;
    }
    float c0r = P[32768 + n*1024 + h],      c0i = P[32768 + n*1024 + 512 + h];
    float c1r = P[32768 + (16+n)*1024 + h], c1i = P[32768 + (16+n)*1024 + 512 + h];
    k0p += c0r*wr - c0i*wi;
    k1p += c1r*wr - c1i*wi;
  }
  kp0[ng][d] = k0p; kp1[ng][d] = k1p;
  __syncthreads();
  if (ng == 0){
    kk0[d] = kp0[0][d]+kp0[1][d]+kp0[2][d]+kp0[3][d];
    kk1[d] = kp1[0][d]+kp1[1][d]+kp1[2][d]+kp1[3][d];
  }
  __syncthreads();
  {
    int r = d;
    u32* wdst = (u32*)(Wbuf + (size_t)h*4096 + r*64);
    int n = r & 15;
    #pragma unroll
    for (int k=0;k<8;++k){
      int s2 = ng*8 + k;
      int s0 = 2*s2, s1 = s0+1;
      float va, vb;
      if      (r < 16){ va = pr[63-s0][n]; vb = pr[63-s1][n]; }
      else if (r < 32){ va = pi[63-s0][n]; vb = pi[63-s1][n]; }
      else if (r < 48){ va = pr[s0][n];    vb = pr[s1][n]; }
      else            { va = pi[s0][n];    vb = pi[s1][n]; }
      wdst[s2] = pack2bf(va, vb);
    }
  }
  {
    int t = d;
    float Dh = Dv[h];
    u32* adst = (u32*)(Abuf + (size_t)h*8192 + t*128);
    #pragma unroll
    for (int k=0;k<8;++k){
      int j2 = ng*8 + k;
      int j0 = 2*j2, j1 = j0+1;
      float va = (j0 < t) ? kk0[t-j0] : ((j0 == t) ? (kk0[0] + Dh) : kk1[j0-t-1]);
      float vb = (j1 < t) ? kk0[t-j1] : ((j1 == t) ? (kk0[0] + Dh) : kk1[j1-t-1]);
      adst[j2] = pack2bf(va, vb);
    }
    #pragma unroll
    for (int j=0;j<4;j+=2){
      int n = ng*4 + j;
      float ar0 = pr[t+1][n],   ai0 = pi[t+1][n];
      float ar1 = pr[t+1][n+1], ai1 = pi[t+1][n+1];
      float br0 = pr[63-t][n],   bi0 = pi[63-t][n];
      float br1 = pr[63-t][n+1], bi1 = pi[63-t][n+1];
      float c0r0 = P[32768 + n*1024 + h],     c0i0 = P[32768 + n*1024 + 512 + h];
      float c0r1 = P[32768 + (n+1)*1024 + h], c0i1 = P[32768 + (n+1)*1024 + 512 + h];
      float c1r0 = P[32768 + (16+n)*1024 + h], c1i0 = P[32768 + (16+n)*1024 + 512 + h];
      float c1r1 = P[32768 + (17+n)*1024 + h], c1i1 = P[32768 + (17+n)*1024 + 512 + h];
      int g = n >> 1;
      adst[32      + g] = pack2bf(c0r0*ar0 - c0i0*ai0,    c0r1*ar1 - c0i1*ai1);
      adst[32 + 8  + g] = pack2bf(-(c0r0*ai0 + c0i0*ar0), -(c0r1*ai1 + c0i1*ar1));
      adst[32 + 16 + g] = pack2bf(c1r0*br0 - c1i0*bi0,    c1r1*br1 - c1i1*bi1);
      adst[32 + 24 + g] = pack2bf(-(c1r0*bi0 + c1i0*br0), -(c1r1*bi1 + c1i1*br1));
    }
  }
}

// ---------------- ssm: fused g1 + p2 + g2, one block per (h, bc-quarter) ------------
// 128 bc (= 2 complete b's) per block; Ul+Vl = 32 KB -> 5 blocks/CU.
// All LDS keys r13-style (bl & 7).
__global__ __launch_bounds__(256) void ssm_kernel(
    const float* __restrict__ P, const u16* __restrict__ Wbuf,
    const u16* __restrict__ Abuf, const u16* __restrict__ uT,
    u16* __restrict__ yT)
{
  __shared__ u16 Ul[128*64];   // 16 KB
  __shared__ u16 Vl[128*64];   // 16 KB
  const int h = blockIdx.x >> 2;
  const int q = blockIdx.x & 3;
  const int tid = threadIdx.x;
  const int wave = tid >> 6, lane = tid & 63;
  const int ro = lane & 15, qq = lane >> 4;
  const int sx = ro & 7;
  const u16* Wh = Wbuf + (size_t)h*4096;
  const u16* Ah = Abuf + (size_t)h*8192;
  const u16* Uh = uT + (size_t)h*BC*64;

  // ---- stage uT tile: 128 bc x 64 t, granule-XOR on global source ----
  #pragma unroll
  for (int i=0; i<4; ++i){
    int r = i*32 + (tid >> 3);    // local bc 0..127
    int gch = tid & 7;
    const u16* src = Uh + ((size_t)(q*128 + r))*64 + ((gch ^ (r & 7)) << 3);
    async16(src, &Ul[i*2048 + tid*8]);
  }
  __syncthreads();
  // ---- g1: Sraw fragments -> Vl (bf16). wave handles 32 bc (nt 0..1). ----
  {
    f32x4 acc[4][2];
    #pragma unroll
    for (int i=0;i<4;i++)
      #pragma unroll
      for (int j=0;j<2;j++)
        #pragma unroll
        for (int k=0;k<4;k++) acc[i][j][k] = 0.f;
    #pragma unroll
    for (int ks=0; ks<2; ++ks){
      int g = ks*4 + qq;
      s16x8 a[4], b[2];
      #pragma unroll
      for (int mt=0; mt<4; ++mt){
        uint4 v = *(const uint4*)(Wh + (mt*16 + ro)*64 + ks*32 + qq*8);
        a[mt] = __builtin_bit_cast(s16x8, v);
      }
      #pragma unroll
      for (int nt=0; nt<2; ++nt){
        int bl = wave*32 + nt*16 + ro;
        uint4 v = *(const uint4*)(&Ul[bl*64 + ((g ^ sx) << 3)]);
        b[nt] = __builtin_bit_cast(s16x8, v);
      }
      #pragma unroll
      for (int mt=0; mt<4; ++mt)
        #pragma unroll
        for (int nt=0; nt<2; ++nt)
          acc[mt][nt] = __builtin_amdgcn_mfma_f32_16x16x32_bf16(a[mt], b[nt], acc[mt][nt], 0, 0, 0);
    }
    #pragma unroll
    for (int mt=0; mt<4; ++mt)
      #pragma unroll
      for (int nt=0; nt<2; ++nt){
        int bl = wave*32 + nt*16 + ro;
        int r0 = mt*16 + qq*4;
        u32 lo = pack2bf(acc[mt][nt][0], acc[mt][nt][1]);
        u32 hi = pack2bf(acc[mt][nt][2], acc[mt][nt][3]);
        int addr = bl*64 + (((r0 >> 3) ^ (bl & 7)) << 3) + (r0 & 7);
        *(uint2*)(&Vl[addr]) = make_uint2(lo, hi);
      }
  }
  __syncthreads();
  // ---- p2: in-LDS inter-chunk scan. 2 waves x 32 active lanes (dir wave-uniform) ----
  if (tid < 128 && (tid & 63) < 32){
    int ln  = tid & 63;
    int dir = tid >> 6;
    int n   = ln & 15;
    int b2  = ln >> 4;            // local b 0..1
    float wLr = P[16384 + n*1024 + h];
    float wLi = P[16384 + n*1024 + 512 + h];
    float Xr = 0.f, Xi = 0.f;
    if (dir == 0){
      int kA = n, kB = 16 + n;
      for (int c=0; c<NCH; ++c){
        int bl = b2*64 + c;
        int aA = bl*64 + (((kA >> 3) ^ (bl & 7)) << 3) + (kA & 7);
        int aB = bl*64 + (((kB >> 3) ^ (bl & 7)) << 3) + (kB & 7);
        float sr = bf2f(Vl[aA]), si = bf2f(Vl[aB]);
        Vl[aA] = f2bf(Xr); Vl[aB] = f2bf(Xi);
        float nr = fmaf(wLr, Xr, fmaf(-wLi, Xi, sr));
        float ni = fmaf(wLr, Xi, fmaf( wLi, Xr, si));
        Xr = nr; Xi = ni;
      }
    } else {
      int kA = 32 + n, kB = 48 + n;
      for (int cc=0; cc<NCH; ++cc){
        int c = NCH-1-cc;
        int bl = b2*64 + c;
        int aA = bl*64 + (((kA >> 3) ^ (bl & 7)) << 3) + (kA & 7);
        int aB = bl*64 + (((kB >> 3) ^ (bl & 7)) << 3) + (kB & 7);
        float sr = bf2f(Vl[aA]), si = bf2f(Vl[aB]);
        Vl[aA] = f2bf(Xr); Vl[aB] = f2bf(Xi);
        float nr = fmaf(wLr, Xr, fmaf(-wLi, Xi, sr));
        float ni = fmaf(wLr, Xi, fmaf( wLi, Xr, si));
        Xr = nr; Xi = ni;
      }
    }
  }
  __syncthreads();
  // ---- g2: y = gelu(A @ [u; V]) -> yT global ----
  {
    f32x4 acc[4][2];
    #pragma unroll
    for (int i=0;i<4;i++)
      #pragma unroll
      for (int j=0;j<2;j++)
        #pragma unroll
        for (int k=0;k<4;k++) acc[i][j][k] = 0.f;
    #pragma unroll
    for (int ks=0; ks<4; ++ks){
      const u16* Bsrc = (ks < 2) ? Ul : Vl;
      int g = (ks & 1)*4 + qq;
      s16x8 a[4], b[2];
      #pragma unroll
      for (int mt=0; mt<4; ++mt){
        uint4 v = *(const uint4*)(Ah + (mt*16 + ro)*128 + ks*32 + qq*8);
        a[mt] = __builtin_bit_cast(s16x8, v);
      }
      #pragma unroll
      for (int nt=0; nt<2; ++nt){
        int bl = wave*32 + nt*16 + ro;
        uint4 v = *(const uint4*)(&Bsrc[bl*64 + ((g ^ sx) << 3)]);
        b[nt] = __builtin_bit_cast(s16x8, v);
      }
      #pragma unroll
      for (int mt=0; mt<4; ++mt)
        #pragma unroll
        for (int nt=0; nt<2; ++nt)
          acc[mt][nt] = __builtin_amdgcn_mfma_f32_16x16x32_bf16(a[mt], b[nt], acc[mt][nt], 0, 0, 0);
    }
    #pragma unroll
    for (int mt=0; mt<4; ++mt)
      #pragma unroll
      for (int nt=0; nt<2; ++nt){
        int bc = q*128 + wave*32 + nt*16 + ro;
        int t0 = mt*16 + qq*4;
        u32 lo = pack2bf(gelu_exact(acc[mt][nt][0]), gelu_exact(acc[mt][nt][1]));
        u32 hi = pack2bf(gelu_exact(acc[mt][nt][2]), gelu_exact(acc[mt][nt][3]));
        *(uint2*)(yT + ((size_t)h*BC + bc)*64 + t0) = make_uint2(lo, hi);
      }
  }
}

// ---------------- T2: yT[h][bc][t] -> uy[b,t,h] -------------------------------------
__global__ __launch_bounds__(256) void t2_kernel(const u16* __restrict__ yT,
                                                 u16* __restrict__ uy)
{
  __shared__ u32 tile[64*257];
  int bc = blockIdx.x, tid = threadIdx.x;
  #pragma unroll
  for (int it=0; it<8; ++it){
    int sg = tid & 7;
    int hp = it*32 + (tid >> 3);
    const u16* s0 = yT + ((size_t)(2*hp)*BC + bc)*64 + sg*8;
    uint4 a = *(const uint4*)s0;
    uint4 b = *(const uint4*)(s0 + (size_t)BC*64);
    u32 ua[4] = {a.x,a.y,a.z,a.w}, ub[4] = {b.x,b.y,b.z,b.w};
    #pragma unroll
    for (int w=0; w<4; ++w){
      u32 lo = (ua[w] & 0xFFFFu) | (ub[w] << 16);
      u32 hi = (ua[w] >> 16) | (ub[w] & 0xFFFF0000u);
      tile[(sg*8 + 2*w    )*257 + hp] = lo;
      tile[(sg*8 + 2*w + 1)*257 + hp] = hi;
    }
  }
  __syncthreads();
  #pragma unroll
  for (int it=0; it<16; ++it){
    int linear = it*256 + tid;
    int t = linear >> 6, sg = linear & 63;
    uint4 v = *(const uint4*)&tile[t*257 + sg*4];
    *(uint4*)(uy + ((size_t)(bc*64 + t) << 9) + sg*8) = v;
  }
}

// ---------------- GEMM (r7 tiling + XCD swizzle + interleaved epilogue) -------------
__global__ __launch_bounds__(256) void gemm_glu_kernel(
    const u16* __restrict__ ybf, const u16* __restrict__ owbf,
    const float* __restrict__ ob, float* __restrict__ hbuf,
    float2* __restrict__ pstat)
{
  __shared__ u16 As[128*64];
  __shared__ u16 Bsh[128*64];
  const int tid = threadIdx.x;
  const int wave = tid >> 6, lane = tid & 63;
  const int x7 = blockIdx.x & 7;
  const int nt = (blockIdx.x >> 3) & 7;
  const int mt = (blockIdx.x >> 6)*8 + x7;
  const int m0 = mt*128, n0 = nt*64;
  const int row = tid >> 3;
  const int ch  = tid & 7;
  f32x4 acc[2][8];
  #pragma unroll
  for (int i=0;i<2;i++)
    #pragma unroll
    for (int j=0;j<8;j++)
      #pragma unroll
      for (int k=0;k<4;k++) acc[i][j][k] = 0.f;

  const int ro = lane & 15, qq = lane >> 4;
  const int sx = ro & 7;
  for (int k0=0;k0<512;k0+=64){
    __syncthreads();
    #pragma unroll
    for (int p=0;p<4;p++){
      int r = p*32 + row;
      int cs = (ch ^ (r & 7)) << 3;
      async16(ybf + ((size_t)(m0+r) << 9) + k0 + cs, &As[(r<<6) + (ch<<3)]);
      int br = n0 + (r & 63) + ((r >> 6) << 9);
      async16(owbf + ((size_t)br << 9) + k0 + cs, &Bsh[(r<<6) + (ch<<3)]);
    }
    __syncthreads();
    #pragma unroll
    for (int ks=0;ks<2;ks++){
      s16x8 a[2], bf[8];
      #pragma unroll
      for (int mi=0;mi<2;mi++){
        int g = ks*4 + qq;
        uint4 t = *(const uint4*)(&As[((wave*32 + mi*16 + ro)<<6) + ((g ^ sx)<<3)]);
        a[mi] = __builtin_bit_cast(s16x8, t);
      }
      #pragma unroll
      for (int ni=0;ni<8;ni++){
        int g = ks*4 + qq;
        uint4 t = *(const uint4*)(&Bsh[((ni*16 + ro)<<6) + ((g ^ sx)<<3)]);
        bf[ni] = __builtin_bit_cast(s16x8, t);
      }
      #pragma unroll
      for (int mi=0;mi<2;mi++)
        #pragma unroll
        for (int ni=0;ni<8;ni++)
          acc[mi][ni] = __builtin_amdgcn_mfma_f32_16x16x32_bf16(a[mi], bf[ni], acc[mi][ni], 0, 0, 0);
    }
  }
  // epilogue (interleaved RMW, fast math)
  float b1v[4], b2v[4];
  #pragma unroll
  for (int ni=0;ni<4;ni++){ b1v[ni] = ob[n0 + ni*16 + ro]; b2v[ni] = ob[n0 + ni*16 + ro + 512]; }
  #pragma unroll
  for (int mi=0;mi<2;mi++){
    #pragma unroll
    for (int rg=0;rg<4;rg++){
      int rowi = m0 + wave*32 + mi*16 + qq*4 + rg;
      float s = 0.f, sq = 0.f;
      #pragma unroll
      for (int ni=0;ni<4;ni++){
        int col = n0 + ni*16 + ro;
        float zz1 = acc[mi][ni][rg] + b1v[ni];
        float zz2 = acc[mi][ni+4][rg] + b2v[ni];
        float g = __fdividef(zz1, 1.f + __expf(-zz2));
        size_t idx = ((size_t)rowi << 9) + col;
        float hn = hbuf[idx] + g;
        hbuf[idx] = hn;
        s += hn; sq += hn*hn;
      }
      #pragma unroll
      for (int off=1; off<16; off<<=1){ s += __shfl_xor(s, off, 64); sq += __shfl_xor(sq, off, 64); }
      if (ro == 0) pstat[(size_t)rowi*8 + nt] = make_float2(s, sq);
    }
  }
}

// ---------------- decoder ----------------------------------------------------------
__global__ __launch_bounds__(256) void decoder_kernel(
    const float* __restrict__ hbuf, const float* __restrict__ dec_w,
    const float* __restrict__ dec_b, float* __restrict__ out)
{
  int wid  = (int)((blockIdx.x*256 + threadIdx.x) >> 6);
  int lane = threadIdx.x & 63;
  const float* p = hbuf + ((size_t)wid << 9) + lane*8;
  float4 a = *(const float4*)p;
  float4 b = *(const float4*)(p+4);
  const float* dw = dec_w + lane*8;
  float4 w0 = *(const float4*)dw;
  float4 w1 = *(const float4*)(dw+4);
  float s = a.x*w0.x + a.y*w0.y + a.z*w0.z + a.w*w0.w
          + b.x*w1.x + b.y*w1.y + b.z*w1.z + b.w*w1.w;
  #pragma unroll
  for (int off=32; off; off>>=1) s += __shfl_xor(s, off, 64);
  if (lane == 0) out[wid] = s + dec_b[0];
}

extern "C" void kernel_launch(void* const* d_in, const int* in_sizes, int n_in,
                              void* d_out, int out_size, void* d_ws, size_t ws_size,
                              hipStream_t stream) {
  const float* x     = (const float*)d_in[0];
  const float* encw  = (const float*)d_in[1];
  const float* encb  = (const float*)d_in[2];
  const float* logdt = (const float*)d_in[3];
  const float* A_re  = (const float*)d_in[4];
  const float* A_im  = (const float*)d_in[5];
  const float* C_re  = (const float*)d_in[6];
  const float* C_im  = (const float*)d_in[7];
  const float* Dv    = (const float*)d_in[8];
  const float* out_w = (const float*)d_in[9];
  const float* out_b = (const float*)d_in[10];
  const float* ln_w  = (const float*)d_in[11];
  const float* ln_b  = (const float*)d_in[12];
  const float* dec_w = (const float*)d_in[13];
  const float* dec_b = (const float*)d_in[14];

  char* ws = (char*)d_ws;
  float*  hbuf   = (float*) (ws);                    //  64 MiB
  u16*    uy     = (u16*)   (ws + 67108864);         //  32 MiB (y for gemm A)
  u16*    uT     = (u16*)   (ws + 100663296);        //  32 MiB
  u16*    yT     = (u16*)   (ws + 134217728);        //  32 MiB
  u16*    owbf   = (u16*)   (ws + 201326592);        //   4 MiB
  float*  params = (float*) (ws + 205520896);        //   1 MiB
  u16*    Abuf   = (u16*)   (ws + 206569472);        //   8 MiB
  u16*    Wbuf   = (u16*)   (ws + 214958080);        //   4 MiB
  float2* pstat  = (float2*)(ws + 219152384);        //   2 MiB (end 221,249,536)

  param_kernel<<<128, 256, 0, stream>>>(logdt, A_re, A_im, C_re, C_im, params);
  owconv_kernel<<<8192, 256, 0, stream>>>(out_w, owbf);
  encoder_kernel<<<8192, 256, 0, stream>>>(x, encw, encb, hbuf, pstat);
  for (int layer=0; layer<NLAYER; ++layer){
    const float* P = params + layer*65536;
    lnt_kernel<<<512, 256, 0, stream>>>(hbuf, pstat, ln_w + layer*HD, ln_b + layer*HD, uT);
    build_kernel<<<512, 256, 0, stream>>>(logdt + layer*HD, A_re + layer*HD*NST,
                                          A_im + layer*HD*NST, P, Dv + layer*HD,
                                          Abuf, Wbuf);
    ssm_kernel<<<2048, 256, 0, stream>>>(P, Wbuf, Abuf, uT, yT);
    t2_kernel<<<512, 256, 0, stream>>>(yT, uy);
    gemm_glu_kernel<<<2048, 256, 0, stream>>>(uy, owbf + (size_t)layer*524288,
                                              out_b + layer*1024, hbuf, pstat);
  }
  decoder_kernel<<<8192, 256, 0, stream>>>(hbuf, dec_w, dec_b, (float*)d_out);
}

// Round 16
// 695.045 us; speedup vs baseline: 1.0086x; 1.0086x over previous
//
#include <hip/hip_runtime.h>

// S4 model (B=8, L=4096, H=512, N=16, 4 layers).
// Round 16:
//  - lnt and t2 split by h-half: LDS 67.5/65.8 KB -> 33 KB, grid 512->1024,
//    4 blocks/CU (were occupancy-capped at 2 blocks/CU).
//  - ssm reverted to r13 half-block geometry (grid 1024, 64 KB LDS) — the
//    best-measured config; r15's quartering was neutral.
//  - gemm unchanged (r14/r15 interleaved epilogue, fast math, XCD swizzle).

typedef __attribute__((ext_vector_type(8))) short s16x8;
typedef __attribute__((ext_vector_type(4))) float f32x4;
typedef unsigned short u16;
typedef unsigned int u32;

#define LSEQ 4096
#define HD   512
#define NST  16
#define NLAYER 4
#define BS   8
#define LC   64
#define NCH  64
#define BC   512   // BS*NCH

static __device__ __forceinline__ u16 f2bf(float f){
  u32 u = __builtin_bit_cast(u32, f);
  u += 0x7FFFu + ((u >> 16) & 1u);
  return (u16)(u >> 16);
}
static __device__ __forceinline__ float bf2f(u16 v){
  u32 u = ((u32)v) << 16;
  return __builtin_bit_cast(float, u);
}
static __device__ __forceinline__ u32 pack2bf(float a, float b){
  return (u32)f2bf(a) | ((u32)f2bf(b) << 16);
}
static __device__ __forceinline__ float gelu_exact(float x){
  float z = fabsf(x) * 0.70710678118654752f;
  float t = 1.f / (1.f + 0.3275911f * z);
  float p = t*(0.254829592f + t*(-0.284496736f + t*(1.421413741f +
            t*(-1.453152027f + t*1.061405429f))));
  float er = 1.f - p * __expf(-z*z);
  er = (x < 0.f) ? -er : er;
  return 0.5f * x * (1.f + er);
}
static __device__ __forceinline__ void async16(const void* g, void* l){
  __builtin_amdgcn_global_load_lds((const __attribute__((address_space(1))) unsigned*)g,
                                   (__attribute__((address_space(3))) unsigned*)l,
                                   16, 0, 0);
}

// ---------------- params: w=exp(dt*A), w^LC, Ct=2*C*(w-1)/A (per layer, 65536 f) ----
__global__ __launch_bounds__(256) void param_kernel(
    const float* __restrict__ log_dt, const float* __restrict__ A_re,
    const float* __restrict__ A_im, const float* __restrict__ C_re,
    const float* __restrict__ C_im, float* __restrict__ params)
{
  int idx = blockIdx.x*256 + threadIdx.x;
  int h = idx & (HD-1);
  int n = (idx >> 9) & (NST-1);
  int layer = idx >> 13;
  float dt  = expf(log_dt[layer*HD + h]);
  float Are = A_re[((layer<<9)+h)*NST + n];
  float Aim = A_im[((layer<<9)+h)*NST + n];
  float ar = Are*dt, ai = Aim*dt;
  float er = expf(ar), sn, cs;
  sincosf(ai, &sn, &cs);
  float wr = er*cs, wi = er*sn;
  float eL = expf((float)LC*ar), snL, csL;
  sincosf((float)LC*ai, &snL, &csL);
  float* P = params + layer*65536;
  P[n*1024 + h]        = wr;
  P[n*1024 + 512 + h]  = wi;
  P[16384 + n*1024 + h]       = eL*csL;
  P[16384 + n*1024 + 512 + h] = eL*snL;
  float den = Are*Are + Aim*Aim;
  float qr = ((wr-1.f)*Are + wi*Aim) / den;
  float qi = (wi*Are - (wr-1.f)*Aim) / den;
  #pragma unroll
  for (int d=0; d<2; d++){
    float Cre = C_re[(((layer*2+d)<<9)+h)*NST + n];
    float Cim = C_im[(((layer*2+d)<<9)+h)*NST + n];
    P[32768 + (d*NST+n)*1024 + h]       = 2.f*(Cre*qr - Cim*qi);
    P[32768 + (d*NST+n)*1024 + 512 + h] = 2.f*(Cre*qi + Cim*qr);
  }
}

__global__ __launch_bounds__(256) void owconv_kernel(const float* __restrict__ ow,
                                                     u16* __restrict__ owbf)
{
  size_t idx = (size_t)blockIdx.x*256 + threadIdx.x;
  owbf[idx] = f2bf(ow[idx]);
}

// ---------------- encoder: row-wise + LN-stat partials -----------------------------
__global__ __launch_bounds__(256) void encoder_kernel(
    const float* __restrict__ x, const float* __restrict__ ew,
    const float* __restrict__ eb, float* __restrict__ hbuf,
    float2* __restrict__ pstat)
{
  int row  = (int)((blockIdx.x*256 + threadIdx.x) >> 6);   // 32768 rows
  int lane = threadIdx.x & 63;
  int t = row & (LSEQ-1);
  int b = row >> 12;
  float xv = x[(b<<12) + t];
  float g = (float)t * (1.0f/4095.0f);
  const float* ewp = ew + lane*16;
  const float* ebp = eb + lane*8;
  float hv[8], s = 0.f, sq = 0.f;
  #pragma unroll
  for (int j=0;j<8;++j){
    float v = xv*ewp[2*j] + g*ewp[2*j+1] + ebp[j];
    hv[j] = v; s += v; sq += v*v;
  }
  float4* hp = (float4*)(hbuf + ((size_t)row << 9) + lane*8);
  hp[0] = make_float4(hv[0],hv[1],hv[2],hv[3]);
  hp[1] = make_float4(hv[4],hv[5],hv[6],hv[7]);
  #pragma unroll
  for (int off=32; off; off>>=1){ s += __shfl_xor(s, off, 64); sq += __shfl_xor(sq, off, 64); }
  if (lane < 8) pstat[(size_t)row*8 + lane] = (lane==0) ? make_float2(s, sq)
                                                        : make_float2(0.f, 0.f);
}

// ---------------- lnt: stats from pstat + apply + transpose, h-half per block -------
__global__ __launch_bounds__(256) void lnt_kernel(
    const float* __restrict__ hbuf, const float2* __restrict__ pstat,
    const float* __restrict__ lnw, const float* __restrict__ lnb,
    u16* __restrict__ uT)
{
  __shared__ u32 tile[256*33];   // 33 KB -> 4 blocks/CU
  __shared__ float smu[64], srs[64];
  int bc = blockIdx.x >> 1, hh = blockIdx.x & 1;
  int tid = threadIdx.x;
  const float* base = hbuf + ((size_t)bc << 15) + hh*256;
  if (tid < 64){
    const float2* pp = pstat + ((size_t)(bc*64 + tid))*8;
    float s = 0.f, sq = 0.f;
    #pragma unroll
    for (int j=0;j<8;++j){ float2 v = pp[j]; s += v.x; sq += v.y; }
    float mu = s*(1.f/512.f);
    float var = sq*(1.f/512.f) - mu*mu;
    smu[tid] = mu; srs[tid] = rsqrtf(var + 1e-5f);
  }
  __syncthreads();
  #pragma unroll
  for (int it=0; it<4; ++it){
    int ho = (tid & 7) + it*8;                 // local h-octet 0..31
    int tp = (tid >> 3) & 31;
    int r0 = 2*tp, r1 = 2*tp + 1;
    float mu0 = smu[r0], rs0 = srs[r0];
    float mu1 = smu[r1], rs1 = srs[r1];
    const float* pa = base + ((size_t)r0 << 9) + ho*8;
    const float* pc = base + ((size_t)r1 << 9) + ho*8;
    float4 a0 = *(const float4*)pa, a1 = *(const float4*)(pa+4);
    float4 c0 = *(const float4*)pc, c1 = *(const float4*)(pc+4);
    const float* pw = lnw + hh*256 + ho*8;
    const float* pb = lnb + hh*256 + ho*8;
    float4 w0 = *(const float4*)pw, w1 = *(const float4*)(pw+4);
    float4 b0 = *(const float4*)pb, b1 = *(const float4*)(pb+4);
    u32* td = &tile[(ho*8)*33 + tp];
    td[0*33] = pack2bf((a0.x-mu0)*rs0*w0.x+b0.x, (c0.x-mu1)*rs1*w0.x+b0.x);
    td[1*33] = pack2bf((a0.y-mu0)*rs0*w0.y+b0.y, (c0.y-mu1)*rs1*w0.y+b0.y);
    td[2*33] = pack2bf((a0.z-mu0)*rs0*w0.z+b0.z, (c0.z-mu1)*rs1*w0.z+b0.z);
    td[3*33] = pack2bf((a0.w-mu0)*rs0*w0.w+b0.w, (c0.w-mu1)*rs1*w0.w+b0.w);
    td[4*33] = pack2bf((a1.x-mu0)*rs0*w1.x+b1.x, (c1.x-mu1)*rs1*w1.x+b1.x);
    td[5*33] = pack2bf((a1.y-mu0)*rs0*w1.y+b1.y, (c1.y-mu1)*rs1*w1.y+b1.y);
    td[6*33] = pack2bf((a1.z-mu0)*rs0*w1.z+b1.z, (c1.z-mu1)*rs1*w1.z+b1.z);
    td[7*33] = pack2bf((a1.w-mu0)*rs0*w1.w+b1.w, (c1.w-mu1)*rs1*w1.w+b1.w);
  }
  __syncthreads();
  #pragma unroll
  for (int it=0; it<8; ++it){
    int linear = it*256 + tid;        // 0..2047
    int lh = linear >> 3, sg = linear & 7;
    uint4 v = *(const uint4*)&tile[lh*33 + sg*4];
    *(uint4*)(uT + ((size_t)(hh*256 + lh)*BC + bc)*64 + sg*8) = v;
  }
}

// ---------------- build: A_h = [M|E] (64x128) and W_h (64x64), bf16, 256 thr -------
__global__ __launch_bounds__(256) void build_kernel(
    const float* __restrict__ logdt, const float* __restrict__ Are_,
    const float* __restrict__ Aim_, const float* __restrict__ P,
    const float* __restrict__ Dv, u16* __restrict__ Abuf, u16* __restrict__ Wbuf)
{
  __shared__ float pr[65][17], pi[65][17];
  __shared__ float kp0[4][64], kp1[4][64];
  __shared__ float kk0[64], kk1[64];
  int h = blockIdx.x;
  int tid = threadIdx.x;
  int d = tid & 63, ng = tid >> 6;
  float dt = expf(logdt[h]);
  float k0p = 0.f, k1p = 0.f;
  #pragma unroll
  for (int j=0; j<4; ++j){
    int n = ng*4 + j;
    float ar = Are_[h*NST+n]*dt, ai = Aim_[h*NST+n]*dt;
    float er = expf(ar*(float)d), sn, cs;
    sincosf(ai*(float)d, &sn, &cs);
    float wr = er*cs, wi = er*sn;
    pr[d][n] = wr; pi[d][n] = wi;
    if (d == 63){
      float er2 = expf(ar*64.f), sn2, cs2;
      sincosf(ai*64.f, &sn2, &cs2);
      pr[64][n] = er2*cs2; pi[64][n] = er2*sn2;
    }
    float c0r = P[32768 + n*1024 + h],      c0i = P[32768 + n*1024 + 512 + h];
    float c1r = P[32768 + (16+n)*1024 + h], c1i = P[32768 + (16+n)*1024 + 512 + h];
    k0p += c0r*wr - c0i*wi;
    k1p += c1r*wr - c1i*wi;
  }
  kp0[ng][d] = k0p; kp1[ng][d] = k1p;
  __syncthreads();
  if (ng == 0){
    kk0[d] = kp0[0][d]+kp0[1][d]+kp0[2][d]+kp0[3][d];
    kk1[d] = kp1[0][d]+kp1[1][d]+kp1[2][d]+kp1[3][d];
  }
  __syncthreads();
  {
    int r = d;
    u32* wdst = (u32*)(Wbuf + (size_t)h*4096 + r*64);
    int n = r & 15;
    #pragma unroll
    for (int k=0;k<8;++k){
      int s2 = ng*8 + k;
      int s0 = 2*s2, s1 = s0+1;
      float va, vb;
      if      (r < 16){ va = pr[63-s0][n]; vb = pr[63-s1][n]; }
      else if (r < 32){ va = pi[63-s0][n]; vb = pi[63-s1][n]; }
      else if (r < 48){ va = pr[s0][n];    vb = pr[s1][n]; }
      else            { va = pi[s0][n];    vb = pi[s1][n]; }
      wdst[s2] = pack2bf(va, vb);
    }
  }
  {
    int t = d;
    float Dh = Dv[h];
    u32* adst = (u32*)(Abuf + (size_t)h*8192 + t*128);
    #pragma unroll
    for (int k=0;k<8;++k){
      int j2 = ng*8 + k;
      int j0 = 2*j2, j1 = j0+1;
      float va = (j0 < t) ? kk0[t-j0] : ((j0 == t) ? (kk0[0] + Dh) : kk1[j0-t-1]);
      float vb = (j1 < t) ? kk0[t-j1] : ((j1 == t) ? (kk0[0] + Dh) : kk1[j1-t-1]);
      adst[j2] = pack2bf(va, vb);
    }
    #pragma unroll
    for (int j=0;j<4;j+=2){
      int n = ng*4 + j;
      float ar0 = pr[t+1][n],   ai0 = pi[t+1][n];
      float ar1 = pr[t+1][n+1], ai1 = pi[t+1][n+1];
      float br0 = pr[63-t][n],   bi0 = pi[63-t][n];
      float br1 = pr[63-t][n+1], bi1 = pi[63-t][n+1];
      float c0r0 = P[32768 + n*1024 + h],     c0i0 = P[32768 + n*1024 + 512 + h];
      float c0r1 = P[32768 + (n+1)*1024 + h], c0i1 = P[32768 + (n+1)*1024 + 512 + h];
      float c1r0 = P[32768 + (16+n)*1024 + h], c1i0 = P[32768 + (16+n)*1024 + 512 + h];
      float c1r1 = P[32768 + (17+n)*1024 + h], c1i1 = P[32768 + (17+n)*1024 + 512 + h];
      int g = n >> 1;
      adst[32      + g] = pack2bf(c0r0*ar0 - c0i0*ai0,    c0r1*ar1 - c0i1*ai1);
      adst[32 + 8  + g] = pack2bf(-(c0r0*ai0 + c0i0*ar0), -(c0r1*ai1 + c0i1*ar1));
      adst[32 + 16 + g] = pack2bf(c1r0*br0 - c1i0*bi0,    c1r1*br1 - c1i1*bi1);
      adst[32 + 24 + g] = pack2bf(-(c1r0*bi0 + c1i0*br0), -(c1r1*bi1 + c1i1*br1));
    }
  }
}

// ---------------- ssm: fused g1 + p2 + g2, one block per (h, bc-half) (r13 geom) ----
__global__ __launch_bounds__(256) void ssm_kernel(
    const float* __restrict__ P, const u16* __restrict__ Wbuf,
    const u16* __restrict__ Abuf, const u16* __restrict__ uT,
    u16* __restrict__ yT)
{
  __shared__ u16 Ul[256*64];
  __shared__ u16 Vl[256*64];
  const int h = blockIdx.x >> 1;
  const int half = blockIdx.x & 1;
  const int tid = threadIdx.x;
  const int wave = tid >> 6, lane = tid & 63;
  const int ro = lane & 15, qq = lane >> 4;
  const int sx = ro & 7;
  const u16* Wh = Wbuf + (size_t)h*4096;
  const u16* Ah = Abuf + (size_t)h*8192;
  const u16* Uh = uT + (size_t)h*BC*64;

  #pragma unroll
  for (int i=0; i<8; ++i){
    int r = i*32 + (tid >> 3);
    int gch = tid & 7;
    const u16* src = Uh + ((size_t)(half*256 + r))*64 + ((gch ^ (r & 7)) << 3);
    async16(src, &Ul[i*2048 + tid*8]);
  }
  __syncthreads();
  // ---- g1 ----
  {
    f32x4 acc[4][4];
    #pragma unroll
    for (int i=0;i<4;i++)
      #pragma unroll
      for (int j=0;j<4;j++)
        #pragma unroll
        for (int k=0;k<4;k++) acc[i][j][k] = 0.f;
    #pragma unroll
    for (int ks=0; ks<2; ++ks){
      int g = ks*4 + qq;
      s16x8 a[4], b[4];
      #pragma unroll
      for (int mt=0; mt<4; ++mt){
        uint4 v = *(const uint4*)(Wh + (mt*16 + ro)*64 + ks*32 + qq*8);
        a[mt] = __builtin_bit_cast(s16x8, v);
      }
      #pragma unroll
      for (int nt=0; nt<4; ++nt){
        int bl = wave*64 + nt*16 + ro;
        uint4 v = *(const uint4*)(&Ul[bl*64 + ((g ^ sx) << 3)]);
        b[nt] = __builtin_bit_cast(s16x8, v);
      }
      #pragma unroll
      for (int mt=0; mt<4; ++mt)
        #pragma unroll
        for (int nt=0; nt<4; ++nt)
          acc[mt][nt] = __builtin_amdgcn_mfma_f32_16x16x32_bf16(a[mt], b[nt], acc[mt][nt], 0, 0, 0);
    }
    #pragma unroll
    for (int mt=0; mt<4; ++mt)
      #pragma unroll
      for (int nt=0; nt<4; ++nt){
        int bl = wave*64 + nt*16 + ro;
        int r0 = mt*16 + qq*4;
        u32 lo = pack2bf(acc[mt][nt][0], acc[mt][nt][1]);
        u32 hi = pack2bf(acc[mt][nt][2], acc[mt][nt][3]);
        int addr = bl*64 + (((r0 >> 3) ^ (bl & 7)) << 3) + (r0 & 7);
        *(uint2*)(&Vl[addr]) = make_uint2(lo, hi);
      }
  }
  __syncthreads();
  // ---- p2 (128 threads: 4b x 16n x 2dir, dir wave-uniform) ----
  if (tid < 128){
    int n   = tid & 15;
    int bl4 = (tid >> 4) & 3;
    int dir = (tid >> 6) & 1;
    float wLr = P[16384 + n*1024 + h];
    float wLi = P[16384 + n*1024 + 512 + h];
    float Xr = 0.f, Xi = 0.f;
    if (dir == 0){
      int kA = n, kB = 16 + n;
      for (int c=0; c<NCH; ++c){
        int bl = bl4*64 + c;
        int aA = bl*64 + (((kA >> 3) ^ (c & 7)) << 3) + (kA & 7);
        int aB = bl*64 + (((kB >> 3) ^ (c & 7)) << 3) + (kB & 7);
        float sr = bf2f(Vl[aA]), si = bf2f(Vl[aB]);
        Vl[aA] = f2bf(Xr); Vl[aB] = f2bf(Xi);
        float nr = fmaf(wLr, Xr, fmaf(-wLi, Xi, sr));
        float ni = fmaf(wLr, Xi, fmaf( wLi, Xr, si));
        Xr = nr; Xi = ni;
      }
    } else {
      int kA = 32 + n, kB = 48 + n;
      for (int cc=0; cc<NCH; ++cc){
        int c = NCH-1-cc;
        int bl = bl4*64 + c;
        int aA = bl*64 + (((kA >> 3) ^ (c & 7)) << 3) + (kA & 7);
        int aB = bl*64 + (((kB >> 3) ^ (c & 7)) << 3) + (kB & 7);
        float sr = bf2f(Vl[aA]), si = bf2f(Vl[aB]);
        Vl[aA] = f2bf(Xr); Vl[aB] = f2bf(Xi);
        float nr = fmaf(wLr, Xr, fmaf(-wLi, Xi, sr));
        float ni = fmaf(wLr, Xi, fmaf( wLi, Xr, si));
        Xr = nr; Xi = ni;
      }
    }
  }
  __syncthreads();
  // ---- g2 ----
  {
    f32x4 acc[4][4];
    #pragma unroll
    for (int i=0;i<4;i++)
      #pragma unroll
      for (int j=0;j<4;j++)
        #pragma unroll
        for (int k=0;k<4;k++) acc[i][j][k] = 0.f;
    #pragma unroll
    for (int ks=0; ks<4; ++ks){
      const u16* Bsrc = (ks < 2) ? Ul : Vl;
      int g = (ks & 1)*4 + qq;
      s16x8 a[4], b[4];
      #pragma unroll
      for (int mt=0; mt<4; ++mt){
        uint4 v = *(const uint4*)(Ah + (mt*16 + ro)*128 + ks*32 + qq*8);
        a[mt] = __builtin_bit_cast(s16x8, v);
      }
      #pragma unroll
      for (int nt=0; nt<4; ++nt){
        int bl = wave*64 + nt*16 + ro;
        uint4 v = *(const uint4*)(&Bsrc[bl*64 + ((g ^ sx) << 3)]);
        b[nt] = __builtin_bit_cast(s16x8, v);
      }
      #pragma unroll
      for (int mt=0; mt<4; ++mt)
        #pragma unroll
        for (int nt=0; nt<4; ++nt)
          acc[mt][nt] = __builtin_amdgcn_mfma_f32_16x16x32_bf16(a[mt], b[nt], acc[mt][nt], 0, 0, 0);
    }
    #pragma unroll
    for (int mt=0; mt<4; ++mt)
      #pragma unroll
      for (int nt=0; nt<4; ++nt){
        int bc = half*256 + wave*64 + nt*16 + ro;
        int t0 = mt*16 + qq*4;
        u32 lo = pack2bf(gelu_exact(acc[mt][nt][0]), gelu_exact(acc[mt][nt][1]));
        u32 hi = pack2bf(gelu_exact(acc[mt][nt][2]), gelu_exact(acc[mt][nt][3]));
        *(uint2*)(yT + ((size_t)h*BC + bc)*64 + t0) = make_uint2(lo, hi);
      }
  }
}

// ---------------- T2: yT[h][bc][t] -> uy[b,t,h], h-half per block -------------------
__global__ __launch_bounds__(256) void t2_kernel(const u16* __restrict__ yT,
                                                 u16* __restrict__ uy)
{
  __shared__ u32 tile[64*129];   // 33 KB -> 4 blocks/CU
  int bc = blockIdx.x >> 1, hh = blockIdx.x & 1;
  int tid = threadIdx.x;
  #pragma unroll
  for (int it=0; it<4; ++it){
    int sg = tid & 7;
    int hp = it*32 + (tid >> 3);            // local h-pair 0..127
    int hpg = hh*128 + hp;
    const u16* s0 = yT + ((size_t)(2*hpg)*BC + bc)*64 + sg*8;
    uint4 a = *(const uint4*)s0;
    uint4 b = *(const uint4*)(s0 + (size_t)BC*64);
    u32 ua[4] = {a.x,a.y,a.z,a.w}, ub[4] = {b.x,b.y,b.z,b.w};
    #pragma unroll
    for (int w=0; w<4; ++w){
      u32 lo = (ua[w] & 0xFFFFu) | (ub[w] << 16);
      u32 hi = (ua[w] >> 16) | (ub[w] & 0xFFFF0000u);
      tile[(sg*8 + 2*w    )*129 + hp] = lo;
      tile[(sg*8 + 2*w + 1)*129 + hp] = hi;
    }
  }
  __syncthreads();
  #pragma unroll
  for (int it=0; it<8; ++it){
    int linear = it*256 + tid;              // 0..2047
    int t = linear >> 5, sg2 = linear & 31;
    uint4 v = *(const uint4*)&tile[t*129 + sg2*4];
    *(uint4*)(uy + ((size_t)(bc*64 + t) << 9) + hh*256 + sg2*8) = v;
  }
}

// ---------------- GEMM (r7 tiling + XCD swizzle + interleaved epilogue) -------------
__global__ __launch_bounds__(256) void gemm_glu_kernel(
    const u16* __restrict__ ybf, const u16* __restrict__ owbf,
    const float* __restrict__ ob, float* __restrict__ hbuf,
    float2* __restrict__ pstat)
{
  __shared__ u16 As[128*64];
  __shared__ u16 Bsh[128*64];
  const int tid = threadIdx.x;
  const int wave = tid >> 6, lane = tid & 63;
  const int x7 = blockIdx.x & 7;
  const int nt = (blockIdx.x >> 3) & 7;
  const int mt = (blockIdx.x >> 6)*8 + x7;
  const int m0 = mt*128, n0 = nt*64;
  const int row = tid >> 3;
  const int ch  = tid & 7;
  f32x4 acc[2][8];
  #pragma unroll
  for (int i=0;i<2;i++)
    #pragma unroll
    for (int j=0;j<8;j++)
      #pragma unroll
      for (int k=0;k<4;k++) acc[i][j][k] = 0.f;

  const int ro = lane & 15, qq = lane >> 4;
  const int sx = ro & 7;
  for (int k0=0;k0<512;k0+=64){
    __syncthreads();
    #pragma unroll
    for (int p=0;p<4;p++){
      int r = p*32 + row;
      int cs = (ch ^ (r & 7)) << 3;
      async16(ybf + ((size_t)(m0+r) << 9) + k0 + cs, &As[(r<<6) + (ch<<3)]);
      int br = n0 + (r & 63) + ((r >> 6) << 9);
      async16(owbf + ((size_t)br << 9) + k0 + cs, &Bsh[(r<<6) + (ch<<3)]);
    }
    __syncthreads();
    #pragma unroll
    for (int ks=0;ks<2;ks++){
      s16x8 a[2], bf[8];
      #pragma unroll
      for (int mi=0;mi<2;mi++){
        int g = ks*4 + qq;
        uint4 t = *(const uint4*)(&As[((wave*32 + mi*16 + ro)<<6) + ((g ^ sx)<<3)]);
        a[mi] = __builtin_bit_cast(s16x8, t);
      }
      #pragma unroll
      for (int ni=0;ni<8;ni++){
        int g = ks*4 + qq;
        uint4 t = *(const uint4*)(&Bsh[((ni*16 + ro)<<6) + ((g ^ sx)<<3)]);
        bf[ni] = __builtin_bit_cast(s16x8, t);
      }
      #pragma unroll
      for (int mi=0;mi<2;mi++)
        #pragma unroll
        for (int ni=0;ni<8;ni++)
          acc[mi][ni] = __builtin_amdgcn_mfma_f32_16x16x32_bf16(a[mi], bf[ni], acc[mi][ni], 0, 0, 0);
    }
  }
  // epilogue (interleaved RMW, fast math)
  float b1v[4], b2v[4];
  #pragma unroll
  for (int ni=0;ni<4;ni++){ b1v[ni] = ob[n0 + ni*16 + ro]; b2v[ni] = ob[n0 + ni*16 + ro + 512]; }
  #pragma unroll
  for (int mi=0;mi<2;mi++){
    #pragma unroll
    for (int rg=0;rg<4;rg++){
      int rowi = m0 + wave*32 + mi*16 + qq*4 + rg;
      float s = 0.f, sq = 0.f;
      #pragma unroll
      for (int ni=0;ni<4;ni++){
        int col = n0 + ni*16 + ro;
        float zz1 = acc[mi][ni][rg] + b1v[ni];
        float zz2 = acc[mi][ni+4][rg] + b2v[ni];
        float g = __fdividef(zz1, 1.f + __expf(-zz2));
        size_t idx = ((size_t)rowi << 9) + col;
        float hn = hbuf[idx] + g;
        hbuf[idx] = hn;
        s += hn; sq += hn*hn;
      }
      #pragma unroll
      for (int off=1; off<16; off<<=1){ s += __shfl_xor(s, off, 64); sq += __shfl_xor(sq, off, 64); }
      if (ro == 0) pstat[(size_t)rowi*8 + nt] = make_float2(s, sq);
    }
  }
}

// ---------------- decoder ----------------------------------------------------------
__global__ __launch_bounds__(256) void decoder_kernel(
    const float* __restrict__ hbuf, const float* __restrict__ dec_w,
    const float* __restrict__ dec_b, float* __restrict__ out)
{
  int wid  = (int)((blockIdx.x*256 + threadIdx.x) >> 6);
  int lane = threadIdx.x & 63;
  const float* p = hbuf + ((size_t)wid << 9) + lane*8;
  float4 a = *(const float4*)p;
  float4 b = *(const float4*)(p+4);
  const float* dw = dec_w + lane*8;
  float4 w0 = *(const float4*)dw;
  float4 w1 = *(const float4*)(dw+4);
  float s = a.x*w0.x + a.y*w0.y + a.z*w0.z + a.w*w0.w
          + b.x*w1.x + b.y*w1.y + b.z*w1.z + b.w*w1.w;
  #pragma unroll
  for (int off=32; off; off>>=1) s += __shfl_xor(s, off, 64);
  if (lane == 0) out[wid] = s + dec_b[0];
}

extern "C" void kernel_launch(void* const* d_in, const int* in_sizes, int n_in,
                              void* d_out, int out_size, void* d_ws, size_t ws_size,
                              hipStream_t stream) {
  const float* x     = (const float*)d_in[0];
  const float* encw  = (const float*)d_in[1];
  const float* encb  = (const float*)d_in[2];
  const float* logdt = (const float*)d_in[3];
  const float* A_re  = (const float*)d_in[4];
  const float* A_im  = (const float*)d_in[5];
  const float* C_re  = (const float*)d_in[6];
  const float* C_im  = (const float*)d_in[7];
  const float* Dv    = (const float*)d_in[8];
  const float* out_w = (const float*)d_in[9];
  const float* out_b = (const float*)d_in[10];
  const float* ln_w  = (const float*)d_in[11];
  const float* ln_b  = (const float*)d_in[12];
  const float* dec_w = (const float*)d_in[13];
  const float* dec_b = (const float*)d_in[14];

  char* ws = (char*)d_ws;
  float*  hbuf   = (float*) (ws);                    //  64 MiB
  u16*    uy     = (u16*)   (ws + 67108864);         //  32 MiB (y for gemm A)
  u16*    uT     = (u16*)   (ws + 100663296);        //  32 MiB
  u16*    yT     = (u16*)   (ws + 134217728);        //  32 MiB
  u16*    owbf   = (u16*)   (ws + 201326592);        //   4 MiB
  float*  params = (float*) (ws + 205520896);        //   1 MiB
  u16*    Abuf   = (u16*)   (ws + 206569472);        //   8 MiB
  u16*    Wbuf   = (u16*)   (ws + 214958080);        //   4 MiB
  float2* pstat  = (float2*)(ws + 219152384);        //   2 MiB (end 221,249,536)

  param_kernel<<<128, 256, 0, stream>>>(logdt, A_re, A_im, C_re, C_im, params);
  owconv_kernel<<<8192, 256, 0, stream>>>(out_w, owbf);
  encoder_kernel<<<8192, 256, 0, stream>>>(x, encw, encb, hbuf, pstat);
  for (int layer=0; layer<NLAYER; ++layer){
    const float* P = params + layer*65536;
    lnt_kernel<<<1024, 256, 0, stream>>>(hbuf, pstat, ln_w + layer*HD, ln_b + layer*HD, uT);
    build_kernel<<<512, 256, 0, stream>>>(logdt + layer*HD, A_re + layer*HD*NST,
                                          A_im + layer*HD*NST, P, Dv + layer*HD,
                                          Abuf, Wbuf);
    ssm_kernel<<<1024, 256, 0, stream>>>(P, Wbuf, Abuf, uT, yT);
    t2_kernel<<<1024, 256, 0, stream>>>(yT, uy);
    gemm_glu_kernel<<<2048, 256, 0, stream>>>(uy, owbf + (size_t)layer*524288,
                                              out_b + layer*1024, hbuf, pstat);
  }
  decoder_kernel<<<8192, 256, 0, stream>>>(hbuf, dec_w, dec_b, (float*)d_out);
}